// Round 11
// baseline (50.068 us; speedup 1.0000x reference)
//
#include <hip/hip_runtime.h>

#define NB 32
#define NH 32
#define NHKV 8
#define NG 4
#define ND 128
#define NP 16
#define NM 128
#define CH 128        // tokens per chunk
#define MAXC 12       // L <= 1500 <= 12*128

// DPP lane-permute helper (VALU pipe — no DS ops). CTRL: quad_perm/row ops.
template<int CTRL>
__device__ __forceinline__ float dppf(float x) {
    return __builtin_bit_cast(float,
        __builtin_amdgcn_update_dpp(0, __builtin_bit_cast(int, x), CTRL, 0xF, 0xF, true));
}
#define DPP_XOR1  0xB1   // [1,0,3,2]
#define DPP_XOR2  0x4E   // [2,3,0,1]
#define DPP_BC0   0x00
#define DPP_BC1   0x55
#define DPP_BC2   0xAA
#define DPP_BC3   0xFF
#define DPP_ROR4  0x124  // row_ror:4
#define DPP_ROR8  0x128  // row_ror:8

// ws_o : float[256][MAXC][NG][ND] unnormalized partial O  (~6.3 MB)
// ws_l : float[256][MAXC][NG]     partial sum of exp      (~49 KB)

__global__ __launch_bounds__(256, 3)   // 168-VGPR cap
void pa_chunk(const float* __restrict__ q,
              const float* __restrict__ knew,
              const float* __restrict__ vnew,
              const float* __restrict__ kc,
              const float* __restrict__ vc,
              const int* __restrict__ bh_seq_lens,
              const int* __restrict__ page_table,
              const int* __restrict__ batch_mapping,
              float* __restrict__ ws_o,
              float* __restrict__ ws_l,
              float* __restrict__ out)
{
    __shared__ int s_pages[CH / NP];                       // 8 pages
    __shared__ __align__(16) float s_part[4][NG][ND];      // 8 KB per-wave partial O
    __shared__ float s_sums[4][NG];

    const int bh = blockIdx.x;
    const int c  = blockIdx.y;
    const int b = bh >> 3;
    const int h = bh & 7;
    const int slot = batch_mapping[b];
    const int seq = bh_seq_lens[slot * NHKV + h];
    const int L = seq + 1;
    const int t0 = c * CH;
    if (t0 >= L) return;
    const int n = min(CH, L - t0);
    const int nc = (L + CH - 1) / CH;
    const int* pt = page_table + (slot * NHKV + h) * NM;

    const int tid = threadIdx.x;
    const int l16 = tid & 15;        // lane within 16-lane token group (== DPP row lane)
    const int grp = tid >> 4;        // token group 0..15

    if (tid < CH / NP) s_pages[tid] = pt[(t0 >> 4) + tid];

    const float scale = 0.08838834764831845f;

    // q fragments pre-scaled by SCALE
    float4 qa[NG], qb[NG];
    #pragma unroll
    for (int g = 0; g < NG; ++g) {
        const float* qp = q + (size_t)(b * NH + h * NG + g) * ND;
        float4 ta = *reinterpret_cast<const float4*>(qp + 4 * l16);
        float4 tb = *reinterpret_cast<const float4*>(qp + 64 + 4 * l16);
        ta.x *= scale; ta.y *= scale; ta.z *= scale; ta.w *= scale;
        tb.x *= scale; tb.y *= scale; tb.z *= scale; tb.w *= scale;
        qa[g] = ta; qb[g] = tb;
    }

    const float4* kc4 = reinterpret_cast<const float4*>(kc);
    const float4* vc4 = reinterpret_cast<const float4*>(vc);
    const float4* knew4 = reinterpret_cast<const float4*>(knew);
    const float4* vnew4 = reinterpret_cast<const float4*>(vnew);

    __syncthreads();   // s_pages ready

    float4 oa[NG] = {{0,0,0,0},{0,0,0,0},{0,0,0,0},{0,0,0,0}};
    float4 ob[NG] = {{0,0,0,0},{0,0,0,0},{0,0,0,0},{0,0,0,0}};
    float psum = 0.f;

    // one token per 16-lane group; zero DS ops in the loop (all cross-lane via DPP)
    auto proc = [&](const float4 ka, const float4 kb,
                    const float4 va, const float4 vb, const bool act) {
        float a0 = qa[0].x*ka.x + qa[0].y*ka.y + qa[0].z*ka.z + qa[0].w*ka.w
                 + qb[0].x*kb.x + qb[0].y*kb.y + qb[0].z*kb.z + qb[0].w*kb.w;
        float a1 = qa[1].x*ka.x + qa[1].y*ka.y + qa[1].z*ka.z + qa[1].w*ka.w
                 + qb[1].x*kb.x + qb[1].y*kb.y + qb[1].z*kb.z + qb[1].w*kb.w;
        float a2 = qa[2].x*ka.x + qa[2].y*ka.y + qa[2].z*ka.z + qa[2].w*ka.w
                 + qb[2].x*kb.x + qb[2].y*kb.y + qb[2].z*kb.z + qb[2].w*kb.w;
        float a3 = qa[3].x*ka.x + qa[3].y*ka.y + qa[3].z*ka.z + qa[3].w*ka.w
                 + qb[3].x*kb.x + qb[3].y*kb.y + qb[3].z*kb.z + qb[3].w*kb.w;
        a0 += dppf<DPP_XOR1>(a0); a1 += dppf<DPP_XOR1>(a1);
        a2 += dppf<DPP_XOR1>(a2); a3 += dppf<DPP_XOR1>(a3);
        a0 += dppf<DPP_XOR2>(a0); a1 += dppf<DPP_XOR2>(a1);
        a2 += dppf<DPP_XOR2>(a2); a3 += dppf<DPP_XOR2>(a3);
        float s = (l16 & 2) ? ((l16 & 1) ? a3 : a2) : ((l16 & 1) ? a1 : a0);
        s += dppf<DPP_ROR4>(s);
        s += dppf<DPP_ROR8>(s);
        const float pe = act ? __expf(s) : 0.f;   // q pre-scaled; |s|<~6: fp32-safe
        psum += pe;
        const float p0 = dppf<DPP_BC0>(pe);
        const float p1 = dppf<DPP_BC1>(pe);
        const float p2 = dppf<DPP_BC2>(pe);
        const float p3 = dppf<DPP_BC3>(pe);
        oa[0].x += p0*va.x; oa[0].y += p0*va.y; oa[0].z += p0*va.z; oa[0].w += p0*va.w;
        ob[0].x += p0*vb.x; ob[0].y += p0*vb.y; ob[0].z += p0*vb.z; ob[0].w += p0*vb.w;
        oa[1].x += p1*va.x; oa[1].y += p1*va.y; oa[1].z += p1*va.z; oa[1].w += p1*va.w;
        ob[1].x += p1*vb.x; ob[1].y += p1*vb.y; ob[1].z += p1*vb.z; ob[1].w += p1*vb.w;
        oa[2].x += p2*va.x; oa[2].y += p2*va.y; oa[2].z += p2*va.z; oa[2].w += p2*va.w;
        ob[2].x += p2*vb.x; ob[2].y += p2*vb.y; ob[2].z += p2*vb.z; ob[2].w += p2*vb.w;
        oa[3].x += p3*va.x; oa[3].y += p3*va.y; oa[3].z += p3*va.z; oa[3].w += p3*va.w;
        ob[3].x += p3*vb.x; ob[3].y += p3*vb.y; ob[3].z += p3*vb.z; ob[3].w += p3*vb.w;
    };

    const bool last_chunk = (t0 + CH >= L);

    if (!last_chunk) {
        // depth-4 software pipeline over the 8 pages; 4-slot circular buffer,
        // fully unrolled so all indices are compile-time (no scratch).
        float4 Ka[4], Kb[4], Va[4], Vb[4];
        #pragma unroll
        for (int p = 0; p < 3; ++p) {
            const size_t r = ((size_t)s_pages[p] * NP + grp) * 32 + l16;
            Ka[p] = kc4[r]; Kb[p] = kc4[r + 16];
            Va[p] = vc4[r]; Vb[p] = vc4[r + 16];
        }
        #pragma unroll
        for (int p = 0; p < CH / NP; ++p) {
            if (p + 3 < CH / NP) {
                const size_t r = ((size_t)s_pages[p + 3] * NP + grp) * 32 + l16;
                Ka[(p + 3) & 3] = kc4[r]; Kb[(p + 3) & 3] = kc4[r + 16];
                Va[(p + 3) & 3] = vc4[r]; Vb[(p + 3) & 3] = vc4[r + 16];
            }
            proc(Ka[p & 3], Kb[p & 3], Va[p & 3], Vb[p & 3], true);
        }
    } else {
        const int nf = (n - 1) & ~(NP - 1);   // full pages strictly before the last token

        // tail-token loads issued FIRST: latency hides under the page loop.
        // (s_pages[t>>4] is always a valid page id, so inactive lanes read safely.)
        const int t = nf + grp;
        const bool act = (t < n);
        const bool isnew = (t0 + t == seq);
        const float4* kp = isnew ? knew4 : kc4;
        const float4* vp = isnew ? vnew4 : vc4;
        const size_t trow = isnew ? (size_t)(b * NHKV + h) * 32
                                  : ((size_t)s_pages[t >> 4] * NP + (t & 15)) * 32;
        const float4 tka = kp[trow + l16];
        const float4 tkb = kp[trow + 16 + l16];
        const float4 tva = vp[trow + l16];
        const float4 tvb = vp[trow + 16 + l16];

        // depth-2 rotating pipeline over the variable-count full pages
        const int npg = nf >> 4;
        if (npg > 0) {
            size_t r = ((size_t)s_pages[0] * NP + grp) * 32 + l16;
            float4 ka = kc4[r], kb = kc4[r + 16];
            float4 va = vc4[r], vb = vc4[r + 16];
            for (int p = 0; p + 1 < npg; ++p) {
                const size_t rn = ((size_t)s_pages[p + 1] * NP + grp) * 32 + l16;
                const float4 nka = kc4[rn], nkb = kc4[rn + 16];
                const float4 nva = vc4[rn], nvb = vc4[rn + 16];
                proc(ka, kb, va, vb, true);
                ka = nka; kb = nkb; va = nva; vb = nvb;
            }
            proc(ka, kb, va, vb, true);
        }
        proc(tka, tkb, tva, tvb, act);
    }

    // reduce across the 4 groups of each wave (once per chunk; DS ok here)
    #pragma unroll
    for (int g = 0; g < NG; ++g) {
        oa[g].x += __shfl_xor(oa[g].x, 16); oa[g].y += __shfl_xor(oa[g].y, 16);
        oa[g].z += __shfl_xor(oa[g].z, 16); oa[g].w += __shfl_xor(oa[g].w, 16);
        ob[g].x += __shfl_xor(ob[g].x, 16); ob[g].y += __shfl_xor(ob[g].y, 16);
        ob[g].z += __shfl_xor(ob[g].z, 16); ob[g].w += __shfl_xor(ob[g].w, 16);
        oa[g].x += __shfl_xor(oa[g].x, 32); oa[g].y += __shfl_xor(oa[g].y, 32);
        oa[g].z += __shfl_xor(oa[g].z, 32); oa[g].w += __shfl_xor(oa[g].w, 32);
        ob[g].x += __shfl_xor(ob[g].x, 32); ob[g].y += __shfl_xor(ob[g].y, 32);
        ob[g].z += __shfl_xor(ob[g].z, 32); ob[g].w += __shfl_xor(ob[g].w, 32);
    }
    psum += __shfl_xor(psum, 16);
    psum += __shfl_xor(psum, 32);

    const int wv = tid >> 6;
    if ((tid & 63) < 16) {
        #pragma unroll
        for (int g = 0; g < NG; ++g) {
            *reinterpret_cast<float4*>(&s_part[wv][g][4 * l16]) = oa[g];
            *reinterpret_cast<float4*>(&s_part[wv][g][64 + 4 * l16]) = ob[g];
        }
    }
    if ((tid & 63) < NG) s_sums[wv][tid & 3] = psum;
    __syncthreads();

    if (nc == 1) {
        // single-chunk bh: normalized output directly, no ws round-trip
        for (int idx = tid; idx < NG * ND; idx += 256) {
            const int g = idx >> 7;
            const int d = idx & 127;
            const float num = s_part[0][g][d] + s_part[1][g][d] + s_part[2][g][d] + s_part[3][g][d];
            const float den = s_sums[0][g] + s_sums[1][g] + s_sums[2][g] + s_sums[3][g];
            out[(size_t)(b * NH + h * NG + g) * ND + d] = num / den;
        }
        return;
    }

    for (int idx = tid; idx < NG * ND; idx += 256) {
        const int g = idx >> 7;
        const int d = idx & 127;
        ws_o[((size_t)(bh * MAXC + c) * NG + g) * ND + d] =
            s_part[0][g][d] + s_part[1][g][d] + s_part[2][g][d] + s_part[3][g][d];
    }
    if (tid < NG) {
        ws_l[(size_t)(bh * MAXC + c) * NG + tid] =
            s_sums[0][tid] + s_sums[1][tid] + s_sums[2][tid] + s_sums[3][tid];
    }
}

__global__ __launch_bounds__(512, 2)
void pa_combine(const float* __restrict__ ws_o,
                const float* __restrict__ ws_l,
                const int* __restrict__ bh_seq_lens,
                const int* __restrict__ batch_mapping,
                float* __restrict__ out)
{
    const int bh = blockIdx.x;
    const int b = bh >> 3;
    const int h = bh & 7;
    const int L = bh_seq_lens[batch_mapping[b] * NHKV + h] + 1;
    const int nc = (L + CH - 1) / CH;
    if (nc == 1) return;                 // chunk kernel wrote out directly

    const int tid = threadIdx.x;
    const int g = tid >> 7;
    const int d = tid & 127;

    float num = 0.f, den = 0.f;
    #pragma unroll
    for (int c = 0; c < MAXC; ++c) {
        if (c < nc) {
            num += ws_o[((size_t)(bh * MAXC + c) * NG + g) * ND + d];
            den += ws_l[(size_t)(bh * MAXC + c) * NG + g];
        }
    }
    out[(size_t)(b * NH + h * NG + g) * ND + d] = num / den;
}

extern "C" void kernel_launch(void* const* d_in, const int* in_sizes, int n_in,
                              void* d_out, int out_size, void* d_ws, size_t ws_size,
                              hipStream_t stream) {
    const float* q    = (const float*)d_in[0];
    const float* knew = (const float*)d_in[1];
    const float* vnew = (const float*)d_in[2];
    const float* kc   = (const float*)d_in[3];
    const float* vc   = (const float*)d_in[4];
    const int* seqls  = (const int*)d_in[5];
    const int* ptab   = (const int*)d_in[6];
    const int* bmap   = (const int*)d_in[7];
    float* out        = (float*)d_out;

    float* ws_o = (float*)d_ws;
    float* ws_l = ws_o + (size_t)NB * NHKV * MAXC * NG * ND;

    dim3 grid(NB * NHKV, MAXC);
    pa_chunk<<<grid, 256, 0, stream>>>(q, knew, vnew, kc, vc, seqls, ptab, bmap,
                                       ws_o, ws_l, out);
    pa_combine<<<NB * NHKV, 512, 0, stream>>>(ws_o, ws_l, seqls, bmap, out);
}

// Round 12
// 41.721 us; speedup vs baseline: 1.2001x; 1.2001x over previous
//
#include <hip/hip_runtime.h>

#define NB 32
#define NH 32
#define NHKV 8
#define NG 4
#define ND 128
#define NP 16
#define NM 128
#define CH 128        // tokens per chunk
#define MAXC 12       // L <= 1500 <= 12*128

// DPP lane-permute helper (VALU pipe — no DS ops). CTRL: quad_perm/row ops.
template<int CTRL>
__device__ __forceinline__ float dppf(float x) {
    return __builtin_bit_cast(float,
        __builtin_amdgcn_update_dpp(0, __builtin_bit_cast(int, x), CTRL, 0xF, 0xF, true));
}
#define DPP_XOR1  0xB1   // [1,0,3,2]
#define DPP_XOR2  0x4E   // [2,3,0,1]
#define DPP_BC0   0x00
#define DPP_BC1   0x55
#define DPP_BC2   0xAA
#define DPP_BC3   0xFF
#define DPP_ROR4  0x124  // row_ror:4
#define DPP_ROR8  0x128  // row_ror:8

// ws_o : float[256][MAXC][NG][ND] unnormalized partial O  (~6.3 MB)
// ws_l : float[256][MAXC][NG]     partial sum of exp      (~49 KB)

__global__ __launch_bounds__(256, 3)   // 168-VGPR cap: depth-3 fits, no spill (R9-validated)
void pa_chunk(const float* __restrict__ q,
              const float* __restrict__ knew,
              const float* __restrict__ vnew,
              const float* __restrict__ kc,
              const float* __restrict__ vc,
              const int* __restrict__ bh_seq_lens,
              const int* __restrict__ page_table,
              const int* __restrict__ batch_mapping,
              float* __restrict__ ws_o,
              float* __restrict__ ws_l,
              float* __restrict__ out)
{
    __shared__ int s_pages[CH / NP];                       // 8 pages
    __shared__ __align__(16) float s_part[4][NG][ND];      // 8 KB per-wave partial O
    __shared__ float s_sums[4][NG];

    const int bh = blockIdx.x;
    const int c  = blockIdx.y;
    const int b = bh >> 3;
    const int h = bh & 7;
    const int slot = batch_mapping[b];
    const int seq = bh_seq_lens[slot * NHKV + h];
    const int L = seq + 1;
    const int t0 = c * CH;
    if (t0 >= L) return;
    const int n = min(CH, L - t0);
    const int nc = (L + CH - 1) / CH;
    const int* pt = page_table + (slot * NHKV + h) * NM;

    const int tid = threadIdx.x;
    const int l16 = tid & 15;        // lane within 16-lane token group (== DPP row lane)
    const int grp = tid >> 4;        // token group 0..15

    if (tid < CH / NP) s_pages[tid] = pt[(t0 >> 4) + tid];

    const float scale = 0.08838834764831845f;

    // q fragments pre-scaled by SCALE
    float4 qa[NG], qb[NG];
    #pragma unroll
    for (int g = 0; g < NG; ++g) {
        const float* qp = q + (size_t)(b * NH + h * NG + g) * ND;
        float4 ta = *reinterpret_cast<const float4*>(qp + 4 * l16);
        float4 tb = *reinterpret_cast<const float4*>(qp + 64 + 4 * l16);
        ta.x *= scale; ta.y *= scale; ta.z *= scale; ta.w *= scale;
        tb.x *= scale; tb.y *= scale; tb.z *= scale; tb.w *= scale;
        qa[g] = ta; qb[g] = tb;
    }

    const float4* kc4 = reinterpret_cast<const float4*>(kc);
    const float4* vc4 = reinterpret_cast<const float4*>(vc);
    const float4* knew4 = reinterpret_cast<const float4*>(knew);
    const float4* vnew4 = reinterpret_cast<const float4*>(vnew);

    __syncthreads();   // s_pages ready

    float4 oa[NG] = {{0,0,0,0},{0,0,0,0},{0,0,0,0},{0,0,0,0}};
    float4 ob[NG] = {{0,0,0,0},{0,0,0,0},{0,0,0,0},{0,0,0,0}};
    float psum = 0.f;

    // one token per 16-lane group; zero DS ops in the loop (all cross-lane via DPP)
    auto proc = [&](const float4 ka, const float4 kb,
                    const float4 va, const float4 vb, const bool act) {
        float a0 = qa[0].x*ka.x + qa[0].y*ka.y + qa[0].z*ka.z + qa[0].w*ka.w
                 + qb[0].x*kb.x + qb[0].y*kb.y + qb[0].z*kb.z + qb[0].w*kb.w;
        float a1 = qa[1].x*ka.x + qa[1].y*ka.y + qa[1].z*ka.z + qa[1].w*ka.w
                 + qb[1].x*kb.x + qb[1].y*kb.y + qb[1].z*kb.z + qb[1].w*kb.w;
        float a2 = qa[2].x*ka.x + qa[2].y*ka.y + qa[2].z*ka.z + qa[2].w*ka.w
                 + qb[2].x*kb.x + qb[2].y*kb.y + qb[2].z*kb.z + qb[2].w*kb.w;
        float a3 = qa[3].x*ka.x + qa[3].y*ka.y + qa[3].z*ka.z + qa[3].w*ka.w
                 + qb[3].x*kb.x + qb[3].y*kb.y + qb[3].z*kb.z + qb[3].w*kb.w;
        a0 += dppf<DPP_XOR1>(a0); a1 += dppf<DPP_XOR1>(a1);
        a2 += dppf<DPP_XOR1>(a2); a3 += dppf<DPP_XOR1>(a3);
        a0 += dppf<DPP_XOR2>(a0); a1 += dppf<DPP_XOR2>(a1);
        a2 += dppf<DPP_XOR2>(a2); a3 += dppf<DPP_XOR2>(a3);
        float s = (l16 & 2) ? ((l16 & 1) ? a3 : a2) : ((l16 & 1) ? a1 : a0);
        s += dppf<DPP_ROR4>(s);
        s += dppf<DPP_ROR8>(s);
        const float pe = act ? __expf(s) : 0.f;   // q pre-scaled; |s|<~6: fp32-safe
        psum += pe;
        const float p0 = dppf<DPP_BC0>(pe);
        const float p1 = dppf<DPP_BC1>(pe);
        const float p2 = dppf<DPP_BC2>(pe);
        const float p3 = dppf<DPP_BC3>(pe);
        oa[0].x += p0*va.x; oa[0].y += p0*va.y; oa[0].z += p0*va.z; oa[0].w += p0*va.w;
        ob[0].x += p0*vb.x; ob[0].y += p0*vb.y; ob[0].z += p0*vb.z; ob[0].w += p0*vb.w;
        oa[1].x += p1*va.x; oa[1].y += p1*va.y; oa[1].z += p1*va.z; oa[1].w += p1*va.w;
        ob[1].x += p1*vb.x; ob[1].y += p1*vb.y; ob[1].z += p1*vb.z; ob[1].w += p1*vb.w;
        oa[2].x += p2*va.x; oa[2].y += p2*va.y; oa[2].z += p2*va.z; oa[2].w += p2*va.w;
        ob[2].x += p2*vb.x; ob[2].y += p2*vb.y; ob[2].z += p2*vb.z; ob[2].w += p2*vb.w;
        oa[3].x += p3*va.x; oa[3].y += p3*va.y; oa[3].z += p3*va.z; oa[3].w += p3*va.w;
        ob[3].x += p3*vb.x; ob[3].y += p3*vb.y; ob[3].z += p3*vb.z; ob[3].w += p3*vb.w;
    };

    const bool last_chunk = (t0 + CH >= L);

    if (!last_chunk) {
        // R9-validated depth-3 pipeline: two pages in flight beyond the consumed one
        size_t r0 = ((size_t)s_pages[0] * NP + grp) * 32 + l16;
        size_t r1 = ((size_t)s_pages[1] * NP + grp) * 32 + l16;
        float4 ka0 = kc4[r0], kb0 = kc4[r0 + 16], va0 = vc4[r0], vb0 = vc4[r0 + 16];
        float4 ka1 = kc4[r1], kb1 = kc4[r1 + 16], va1 = vc4[r1], vb1 = vc4[r1 + 16];
        #pragma unroll 2
        for (int p = 0; p < CH / NP - 2; ++p) {
            const size_t rn = ((size_t)s_pages[p + 2] * NP + grp) * 32 + l16;
            const float4 nka = kc4[rn], nkb = kc4[rn + 16];
            const float4 nva = vc4[rn], nvb = vc4[rn + 16];
            proc(ka0, kb0, va0, vb0, true);
            ka0 = ka1; kb0 = kb1; va0 = va1; vb0 = vb1;
            ka1 = nka; kb1 = nkb; va1 = nva; vb1 = nvb;
        }
        proc(ka0, kb0, va0, vb0, true);
        proc(ka1, kb1, va1, vb1, true);
    } else {
        const int nf = (n - 1) & ~(NP - 1);   // full pages strictly before the last token

        // tail-token loads issued FIRST: latency hides under the page loop.
        // (s_pages[t>>4] is always a valid page id, so inactive lanes read safely.)
        const int t = nf + grp;
        const bool act = (t < n);
        const bool isnew = (t0 + t == seq);
        const float4* kp = isnew ? knew4 : kc4;
        const float4* vp = isnew ? vnew4 : vc4;
        const size_t trow = isnew ? (size_t)(b * NHKV + h) * 32
                                  : ((size_t)s_pages[t >> 4] * NP + (t & 15)) * 32;
        const float4 tka = kp[trow + l16];
        const float4 tkb = kp[trow + 16 + l16];
        const float4 tva = vp[trow + l16];
        const float4 tvb = vp[trow + 16 + l16];

        // depth-2 rotating pipeline over the variable-count full pages
        const int npg = nf >> 4;
        if (npg > 0) {
            size_t r = ((size_t)s_pages[0] * NP + grp) * 32 + l16;
            float4 ka = kc4[r], kb = kc4[r + 16];
            float4 va = vc4[r], vb = vc4[r + 16];
            for (int p = 0; p + 1 < npg; ++p) {
                const size_t rn = ((size_t)s_pages[p + 1] * NP + grp) * 32 + l16;
                const float4 nka = kc4[rn], nkb = kc4[rn + 16];
                const float4 nva = vc4[rn], nvb = vc4[rn + 16];
                proc(ka, kb, va, vb, true);
                ka = nka; kb = nkb; va = nva; vb = nvb;
            }
            proc(ka, kb, va, vb, true);
        }
        proc(tka, tkb, tva, tvb, act);
    }

    // reduce across the 4 groups of each wave (once per chunk; DS ok here)
    #pragma unroll
    for (int g = 0; g < NG; ++g) {
        oa[g].x += __shfl_xor(oa[g].x, 16); oa[g].y += __shfl_xor(oa[g].y, 16);
        oa[g].z += __shfl_xor(oa[g].z, 16); oa[g].w += __shfl_xor(oa[g].w, 16);
        ob[g].x += __shfl_xor(ob[g].x, 16); ob[g].y += __shfl_xor(ob[g].y, 16);
        ob[g].z += __shfl_xor(ob[g].z, 16); ob[g].w += __shfl_xor(ob[g].w, 16);
        oa[g].x += __shfl_xor(oa[g].x, 32); oa[g].y += __shfl_xor(oa[g].y, 32);
        oa[g].z += __shfl_xor(oa[g].z, 32); oa[g].w += __shfl_xor(oa[g].w, 32);
        ob[g].x += __shfl_xor(ob[g].x, 32); ob[g].y += __shfl_xor(ob[g].y, 32);
        ob[g].z += __shfl_xor(ob[g].z, 32); ob[g].w += __shfl_xor(ob[g].w, 32);
    }
    psum += __shfl_xor(psum, 16);
    psum += __shfl_xor(psum, 32);

    const int wv = tid >> 6;
    if ((tid & 63) < 16) {
        #pragma unroll
        for (int g = 0; g < NG; ++g) {
            *reinterpret_cast<float4*>(&s_part[wv][g][4 * l16]) = oa[g];
            *reinterpret_cast<float4*>(&s_part[wv][g][64 + 4 * l16]) = ob[g];
        }
    }
    if ((tid & 63) < NG) s_sums[wv][tid & 3] = psum;
    __syncthreads();

    if (nc == 1) {
        // single-chunk bh: normalized output directly, no ws round-trip
        for (int idx = tid; idx < NG * ND; idx += 256) {
            const int g = idx >> 7;
            const int d = idx & 127;
            const float num = s_part[0][g][d] + s_part[1][g][d] + s_part[2][g][d] + s_part[3][g][d];
            const float den = s_sums[0][g] + s_sums[1][g] + s_sums[2][g] + s_sums[3][g];
            out[(size_t)(b * NH + h * NG + g) * ND + d] = num / den;
        }
        return;
    }

    for (int idx = tid; idx < NG * ND; idx += 256) {
        const int g = idx >> 7;
        const int d = idx & 127;
        ws_o[((size_t)(bh * MAXC + c) * NG + g) * ND + d] =
            s_part[0][g][d] + s_part[1][g][d] + s_part[2][g][d] + s_part[3][g][d];
    }
    if (tid < NG) {
        ws_l[(size_t)(bh * MAXC + c) * NG + tid] =
            s_sums[0][tid] + s_sums[1][tid] + s_sums[2][tid] + s_sums[3][tid];
    }
}

__global__ __launch_bounds__(512, 2)
void pa_combine(const float* __restrict__ ws_o,
                const float* __restrict__ ws_l,
                const int* __restrict__ bh_seq_lens,
                const int* __restrict__ batch_mapping,
                float* __restrict__ out)
{
    const int bh = blockIdx.x;
    const int b = bh >> 3;
    const int h = bh & 7;
    const int L = bh_seq_lens[batch_mapping[b] * NHKV + h] + 1;
    const int nc = (L + CH - 1) / CH;
    if (nc == 1) return;                 // chunk kernel wrote out directly

    const int tid = threadIdx.x;
    const int g = tid >> 7;
    const int d = tid & 127;

    float num = 0.f, den = 0.f;
    #pragma unroll
    for (int c = 0; c < MAXC; ++c) {
        if (c < nc) {
            num += ws_o[((size_t)(bh * MAXC + c) * NG + g) * ND + d];
            den += ws_l[(size_t)(bh * MAXC + c) * NG + g];
        }
    }
    out[(size_t)(b * NH + h * NG + g) * ND + d] = num / den;
}

extern "C" void kernel_launch(void* const* d_in, const int* in_sizes, int n_in,
                              void* d_out, int out_size, void* d_ws, size_t ws_size,
                              hipStream_t stream) {
    const float* q    = (const float*)d_in[0];
    const float* knew = (const float*)d_in[1];
    const float* vnew = (const float*)d_in[2];
    const float* kc   = (const float*)d_in[3];
    const float* vc   = (const float*)d_in[4];
    const int* seqls  = (const int*)d_in[5];
    const int* ptab   = (const int*)d_in[6];
    const int* bmap   = (const int*)d_in[7];
    float* out        = (float*)d_out;

    float* ws_o = (float*)d_ws;
    float* ws_l = ws_o + (size_t)NB * NHKV * MAXC * NG * ND;

    dim3 grid(NB * NHKV, MAXC);
    pa_chunk<<<grid, 256, 0, stream>>>(q, knew, vnew, kc, vc, seqls, ptab, bmap,
                                       ws_o, ws_l, out);
    pa_combine<<<NB * NHKV, 512, 0, stream>>>(ws_o, ws_l, seqls, bmap, out);
}

// Round 13
// 41.606 us; speedup vs baseline: 1.2034x; 1.0027x over previous
//
#include <hip/hip_runtime.h>

#define NB 32
#define NH 32
#define NHKV 8
#define NG 4
#define ND 128
#define NP 16
#define NM 128
#define CH 256        // tokens per chunk (R12: was 128)
#define MAXC 6        // L <= 1500 <= 6*256

// DPP lane-permute helper (VALU pipe — no DS ops). CTRL: quad_perm/row ops.
template<int CTRL>
__device__ __forceinline__ float dppf(float x) {
    return __builtin_bit_cast(float,
        __builtin_amdgcn_update_dpp(0, __builtin_bit_cast(int, x), CTRL, 0xF, 0xF, true));
}
#define DPP_XOR1  0xB1   // [1,0,3,2]
#define DPP_XOR2  0x4E   // [2,3,0,1]
#define DPP_BC0   0x00
#define DPP_BC1   0x55
#define DPP_BC2   0xAA
#define DPP_BC3   0xFF
#define DPP_ROR4  0x124  // row_ror:4
#define DPP_ROR8  0x128  // row_ror:8

// ws_o : float[256][MAXC][NG][ND] unnormalized partial O  (~3.1 MB)
// ws_l : float[256][MAXC][NG]     partial sum of exp      (~25 KB)

__global__ __launch_bounds__(256, 3)   // 168-VGPR cap: depth-3 fits, no spill (R9-validated)
void pa_chunk(const float* __restrict__ q,
              const float* __restrict__ knew,
              const float* __restrict__ vnew,
              const float* __restrict__ kc,
              const float* __restrict__ vc,
              const int* __restrict__ bh_seq_lens,
              const int* __restrict__ page_table,
              const int* __restrict__ batch_mapping,
              float* __restrict__ ws_o,
              float* __restrict__ ws_l,
              float* __restrict__ out)
{
    __shared__ int s_pages[CH / NP];                       // 16 pages
    __shared__ __align__(16) float s_part[4][NG][ND];      // 8 KB per-wave partial O
    __shared__ float s_sums[4][NG];

    const int bh = blockIdx.x;
    const int c  = blockIdx.y;
    const int b = bh >> 3;
    const int h = bh & 7;
    const int slot = batch_mapping[b];
    const int seq = bh_seq_lens[slot * NHKV + h];
    const int L = seq + 1;
    const int t0 = c * CH;
    if (t0 >= L) return;
    const int n = min(CH, L - t0);
    const int nc = (L + CH - 1) / CH;
    const int* pt = page_table + (slot * NHKV + h) * NM;

    const int tid = threadIdx.x;
    const int l16 = tid & 15;        // lane within 16-lane token group (== DPP row lane)
    const int grp = tid >> 4;        // token group 0..15

    if (tid < CH / NP) s_pages[tid] = pt[(t0 >> 4) + tid];

    const float scale = 0.08838834764831845f;

    // q fragments pre-scaled by SCALE
    float4 qa[NG], qb[NG];
    #pragma unroll
    for (int g = 0; g < NG; ++g) {
        const float* qp = q + (size_t)(b * NH + h * NG + g) * ND;
        float4 ta = *reinterpret_cast<const float4*>(qp + 4 * l16);
        float4 tb = *reinterpret_cast<const float4*>(qp + 64 + 4 * l16);
        ta.x *= scale; ta.y *= scale; ta.z *= scale; ta.w *= scale;
        tb.x *= scale; tb.y *= scale; tb.z *= scale; tb.w *= scale;
        qa[g] = ta; qb[g] = tb;
    }

    const float4* kc4 = reinterpret_cast<const float4*>(kc);
    const float4* vc4 = reinterpret_cast<const float4*>(vc);
    const float4* knew4 = reinterpret_cast<const float4*>(knew);
    const float4* vnew4 = reinterpret_cast<const float4*>(vnew);

    __syncthreads();   // s_pages ready

    float4 oa[NG] = {{0,0,0,0},{0,0,0,0},{0,0,0,0},{0,0,0,0}};
    float4 ob[NG] = {{0,0,0,0},{0,0,0,0},{0,0,0,0},{0,0,0,0}};
    float psum = 0.f;

    // one token per 16-lane group; zero DS ops in the loop (all cross-lane via DPP)
    auto proc = [&](const float4 ka, const float4 kb,
                    const float4 va, const float4 vb, const bool act) {
        float a0 = qa[0].x*ka.x + qa[0].y*ka.y + qa[0].z*ka.z + qa[0].w*ka.w
                 + qb[0].x*kb.x + qb[0].y*kb.y + qb[0].z*kb.z + qb[0].w*kb.w;
        float a1 = qa[1].x*ka.x + qa[1].y*ka.y + qa[1].z*ka.z + qa[1].w*ka.w
                 + qb[1].x*kb.x + qb[1].y*kb.y + qb[1].z*kb.z + qb[1].w*kb.w;
        float a2 = qa[2].x*ka.x + qa[2].y*ka.y + qa[2].z*ka.z + qa[2].w*ka.w
                 + qb[2].x*kb.x + qb[2].y*kb.y + qb[2].z*kb.z + qb[2].w*kb.w;
        float a3 = qa[3].x*ka.x + qa[3].y*ka.y + qa[3].z*ka.z + qa[3].w*ka.w
                 + qb[3].x*kb.x + qb[3].y*kb.y + qb[3].z*kb.z + qb[3].w*kb.w;
        a0 += dppf<DPP_XOR1>(a0); a1 += dppf<DPP_XOR1>(a1);
        a2 += dppf<DPP_XOR1>(a2); a3 += dppf<DPP_XOR1>(a3);
        a0 += dppf<DPP_XOR2>(a0); a1 += dppf<DPP_XOR2>(a1);
        a2 += dppf<DPP_XOR2>(a2); a3 += dppf<DPP_XOR2>(a3);
        float s = (l16 & 2) ? ((l16 & 1) ? a3 : a2) : ((l16 & 1) ? a1 : a0);
        s += dppf<DPP_ROR4>(s);
        s += dppf<DPP_ROR8>(s);
        const float pe = act ? __expf(s) : 0.f;   // q pre-scaled; |s|<~6: fp32-safe
        psum += pe;
        const float p0 = dppf<DPP_BC0>(pe);
        const float p1 = dppf<DPP_BC1>(pe);
        const float p2 = dppf<DPP_BC2>(pe);
        const float p3 = dppf<DPP_BC3>(pe);
        oa[0].x += p0*va.x; oa[0].y += p0*va.y; oa[0].z += p0*va.z; oa[0].w += p0*va.w;
        ob[0].x += p0*vb.x; ob[0].y += p0*vb.y; ob[0].z += p0*vb.z; ob[0].w += p0*vb.w;
        oa[1].x += p1*va.x; oa[1].y += p1*va.y; oa[1].z += p1*va.z; oa[1].w += p1*va.w;
        ob[1].x += p1*vb.x; ob[1].y += p1*vb.y; ob[1].z += p1*vb.z; ob[1].w += p1*vb.w;
        oa[2].x += p2*va.x; oa[2].y += p2*va.y; oa[2].z += p2*va.z; oa[2].w += p2*va.w;
        ob[2].x += p2*vb.x; ob[2].y += p2*vb.y; ob[2].z += p2*vb.z; ob[2].w += p2*vb.w;
        oa[3].x += p3*va.x; oa[3].y += p3*va.y; oa[3].z += p3*va.z; oa[3].w += p3*va.w;
        ob[3].x += p3*vb.x; ob[3].y += p3*vb.y; ob[3].z += p3*vb.z; ob[3].w += p3*vb.w;
    };

    const bool last_chunk = (t0 + CH >= L);

    if (!last_chunk) {
        // depth-3 pipeline: two pages in flight beyond the consumed one
        size_t r0 = ((size_t)s_pages[0] * NP + grp) * 32 + l16;
        size_t r1 = ((size_t)s_pages[1] * NP + grp) * 32 + l16;
        float4 ka0 = kc4[r0], kb0 = kc4[r0 + 16], va0 = vc4[r0], vb0 = vc4[r0 + 16];
        float4 ka1 = kc4[r1], kb1 = kc4[r1 + 16], va1 = vc4[r1], vb1 = vc4[r1 + 16];
        #pragma unroll 2
        for (int p = 0; p < CH / NP - 2; ++p) {
            const size_t rn = ((size_t)s_pages[p + 2] * NP + grp) * 32 + l16;
            const float4 nka = kc4[rn], nkb = kc4[rn + 16];
            const float4 nva = vc4[rn], nvb = vc4[rn + 16];
            proc(ka0, kb0, va0, vb0, true);
            ka0 = ka1; kb0 = kb1; va0 = va1; vb0 = vb1;
            ka1 = nka; kb1 = nkb; va1 = nva; vb1 = nvb;
        }
        proc(ka0, kb0, va0, vb0, true);
        proc(ka1, kb1, va1, vb1, true);
    } else {
        const int nf = (n - 1) & ~(NP - 1);   // full pages strictly before the last token

        // tail-token loads issued FIRST: latency hides under the page loop.
        const int t = nf + grp;
        const bool act = (t < n);
        const bool isnew = (t0 + t == seq);
        const float4* kp = isnew ? knew4 : kc4;
        const float4* vp = isnew ? vnew4 : vc4;
        const size_t trow = isnew ? (size_t)(b * NHKV + h) * 32
                                  : ((size_t)s_pages[t >> 4] * NP + (t & 15)) * 32;
        const float4 tka = kp[trow + l16];
        const float4 tkb = kp[trow + 16 + l16];
        const float4 tva = vp[trow + l16];
        const float4 tvb = vp[trow + 16 + l16];

        // depth-2 rotating pipeline over the variable-count full pages
        const int npg = nf >> 4;
        if (npg > 0) {
            size_t r = ((size_t)s_pages[0] * NP + grp) * 32 + l16;
            float4 ka = kc4[r], kb = kc4[r + 16];
            float4 va = vc4[r], vb = vc4[r + 16];
            for (int p = 0; p + 1 < npg; ++p) {
                const size_t rn = ((size_t)s_pages[p + 1] * NP + grp) * 32 + l16;
                const float4 nka = kc4[rn], nkb = kc4[rn + 16];
                const float4 nva = vc4[rn], nvb = vc4[rn + 16];
                proc(ka, kb, va, vb, true);
                ka = nka; kb = nkb; va = nva; vb = nvb;
            }
            proc(ka, kb, va, vb, true);
        }
        proc(tka, tkb, tva, tvb, act);
    }

    // reduce across the 4 groups of each wave (once per chunk; DS ok here)
    #pragma unroll
    for (int g = 0; g < NG; ++g) {
        oa[g].x += __shfl_xor(oa[g].x, 16); oa[g].y += __shfl_xor(oa[g].y, 16);
        oa[g].z += __shfl_xor(oa[g].z, 16); oa[g].w += __shfl_xor(oa[g].w, 16);
        ob[g].x += __shfl_xor(ob[g].x, 16); ob[g].y += __shfl_xor(ob[g].y, 16);
        ob[g].z += __shfl_xor(ob[g].z, 16); ob[g].w += __shfl_xor(ob[g].w, 16);
        oa[g].x += __shfl_xor(oa[g].x, 32); oa[g].y += __shfl_xor(oa[g].y, 32);
        oa[g].z += __shfl_xor(oa[g].z, 32); oa[g].w += __shfl_xor(oa[g].w, 32);
        ob[g].x += __shfl_xor(ob[g].x, 32); ob[g].y += __shfl_xor(ob[g].y, 32);
        ob[g].z += __shfl_xor(ob[g].z, 32); ob[g].w += __shfl_xor(ob[g].w, 32);
    }
    psum += __shfl_xor(psum, 16);
    psum += __shfl_xor(psum, 32);

    const int wv = tid >> 6;
    if ((tid & 63) < 16) {
        #pragma unroll
        for (int g = 0; g < NG; ++g) {
            *reinterpret_cast<float4*>(&s_part[wv][g][4 * l16]) = oa[g];
            *reinterpret_cast<float4*>(&s_part[wv][g][64 + 4 * l16]) = ob[g];
        }
    }
    if ((tid & 63) < NG) s_sums[wv][tid & 3] = psum;
    __syncthreads();

    if (nc == 1) {
        // single-chunk bh: normalized output directly, no ws round-trip
        for (int idx = tid; idx < NG * ND; idx += 256) {
            const int g = idx >> 7;
            const int d = idx & 127;
            const float num = s_part[0][g][d] + s_part[1][g][d] + s_part[2][g][d] + s_part[3][g][d];
            const float den = s_sums[0][g] + s_sums[1][g] + s_sums[2][g] + s_sums[3][g];
            out[(size_t)(b * NH + h * NG + g) * ND + d] = num / den;
        }
        return;
    }

    for (int idx = tid; idx < NG * ND; idx += 256) {
        const int g = idx >> 7;
        const int d = idx & 127;
        ws_o[((size_t)(bh * MAXC + c) * NG + g) * ND + d] =
            s_part[0][g][d] + s_part[1][g][d] + s_part[2][g][d] + s_part[3][g][d];
    }
    if (tid < NG) {
        ws_l[(size_t)(bh * MAXC + c) * NG + tid] =
            s_sums[0][tid] + s_sums[1][tid] + s_sums[2][tid] + s_sums[3][tid];
    }
}

__global__ __launch_bounds__(512, 2)
void pa_combine(const float* __restrict__ ws_o,
                const float* __restrict__ ws_l,
                const int* __restrict__ bh_seq_lens,
                const int* __restrict__ batch_mapping,
                float* __restrict__ out)
{
    const int bh = blockIdx.x;
    const int b = bh >> 3;
    const int h = bh & 7;
    const int L = bh_seq_lens[batch_mapping[b] * NHKV + h] + 1;
    const int nc = (L + CH - 1) / CH;
    if (nc == 1) return;                 // chunk kernel wrote out directly

    const int tid = threadIdx.x;
    const int g = tid >> 7;
    const int d = tid & 127;

    float num = 0.f, den = 0.f;
    #pragma unroll
    for (int c = 0; c < MAXC; ++c) {
        if (c < nc) {
            num += ws_o[((size_t)(bh * MAXC + c) * NG + g) * ND + d];
            den += ws_l[(size_t)(bh * MAXC + c) * NG + g];
        }
    }
    out[(size_t)(b * NH + h * NG + g) * ND + d] = num / den;
}

extern "C" void kernel_launch(void* const* d_in, const int* in_sizes, int n_in,
                              void* d_out, int out_size, void* d_ws, size_t ws_size,
                              hipStream_t stream) {
    const float* q    = (const float*)d_in[0];
    const float* knew = (const float*)d_in[1];
    const float* vnew = (const float*)d_in[2];
    const float* kc   = (const float*)d_in[3];
    const float* vc   = (const float*)d_in[4];
    const int* seqls  = (const int*)d_in[5];
    const int* ptab   = (const int*)d_in[6];
    const int* bmap   = (const int*)d_in[7];
    float* out        = (float*)d_out;

    float* ws_o = (float*)d_ws;
    float* ws_l = ws_o + (size_t)NB * NHKV * MAXC * NG * ND;

    dim3 grid(NB * NHKV, MAXC);
    pa_chunk<<<grid, 256, 0, stream>>>(q, knew, vnew, kc, vc, seqls, ptab, bmap,
                                       ws_o, ws_l, out);
    pa_combine<<<NB * NHKV, 512, 0, stream>>>(ws_o, ws_l, seqls, bmap, out);
}

// Round 15
// 41.419 us; speedup vs baseline: 1.2088x; 1.0045x over previous
//
#include <hip/hip_runtime.h>

#define NB 32
#define NH 32
#define NHKV 8
#define NG 4
#define ND 128
#define NP 16
#define NM 128
#define CH 256        // tokens per chunk
#define MAXC 6        // L <= 1500 <= 6*256

// DPP lane-permute helper (VALU pipe — no DS ops). CTRL: quad_perm/row ops.
template<int CTRL>
__device__ __forceinline__ float dppf(float x) {
    return __builtin_bit_cast(float,
        __builtin_amdgcn_update_dpp(0, __builtin_bit_cast(int, x), CTRL, 0xF, 0xF, true));
}
#define DPP_XOR1  0xB1   // [1,0,3,2]
#define DPP_XOR2  0x4E   // [2,3,0,1]
#define DPP_BC0   0x00
#define DPP_BC1   0x55
#define DPP_BC2   0xAA
#define DPP_BC3   0xFF
#define DPP_ROR4  0x124  // row_ror:4
#define DPP_ROR8  0x128  // row_ror:8

// ws_o : float[256][MAXC][NG][ND] unnormalized partial O  (~3.1 MB)
// ws_l : float[256][MAXC][NG]     partial sum of exp      (~25 KB)

__global__ __launch_bounds__(256, 3)   // 168-VGPR cap: depth-3 fits, no spill (R9/R12-validated)
void pa_chunk(const float* __restrict__ q,
              const float* __restrict__ knew,
              const float* __restrict__ vnew,
              const float* __restrict__ kc,
              const float* __restrict__ vc,
              const int* __restrict__ bh_seq_lens,
              const int* __restrict__ page_table,
              const int* __restrict__ batch_mapping,
              float* __restrict__ ws_o,
              float* __restrict__ ws_l,
              float* __restrict__ out)
{
    __shared__ int s_pages[CH / NP];                       // 16 pages
    __shared__ __align__(16) float s_part[4][NG][ND];      // 8 KB per-wave partial O
    __shared__ float s_sums[4][NG];

    const int bh = blockIdx.x;
    const int c  = blockIdx.y;
    const int b = bh >> 3;
    const int h = bh & 7;
    const int slot = batch_mapping[b];
    const int seq = bh_seq_lens[slot * NHKV + h];
    const int L = seq + 1;
    const int t0 = c * CH;
    if (t0 >= L) return;
    const int n = min(CH, L - t0);
    const int nc = (L + CH - 1) / CH;
    const int* pt = page_table + (slot * NHKV + h) * NM;

    const int tid = threadIdx.x;
    const int l16 = tid & 15;        // lane within 16-lane token group (== DPP row lane)
    const int grp = tid >> 4;        // token group 0..15

    if (tid < CH / NP) s_pages[tid] = pt[(t0 >> 4) + tid];

    const float scale = 0.08838834764831845f;

    // q fragments pre-scaled by SCALE
    float4 qa[NG], qb[NG];
    #pragma unroll
    for (int g = 0; g < NG; ++g) {
        const float* qp = q + (size_t)(b * NH + h * NG + g) * ND;
        float4 ta = *reinterpret_cast<const float4*>(qp + 4 * l16);
        float4 tb = *reinterpret_cast<const float4*>(qp + 64 + 4 * l16);
        ta.x *= scale; ta.y *= scale; ta.z *= scale; ta.w *= scale;
        tb.x *= scale; tb.y *= scale; tb.z *= scale; tb.w *= scale;
        qa[g] = ta; qb[g] = tb;
    }

    const float4* kc4 = reinterpret_cast<const float4*>(kc);
    const float4* vc4 = reinterpret_cast<const float4*>(vc);
    const float4* knew4 = reinterpret_cast<const float4*>(knew);
    const float4* vnew4 = reinterpret_cast<const float4*>(vnew);

    __syncthreads();   // s_pages ready

    float4 oa[NG] = {{0,0,0,0},{0,0,0,0},{0,0,0,0},{0,0,0,0}};
    float4 ob[NG] = {{0,0,0,0},{0,0,0,0},{0,0,0,0},{0,0,0,0}};
    float psum = 0.f;

    // one token per 16-lane group; zero DS ops in the loop (all cross-lane via DPP)
    auto proc = [&](const float4 ka, const float4 kb,
                    const float4 va, const float4 vb, const bool act) {
        float a0 = qa[0].x*ka.x + qa[0].y*ka.y + qa[0].z*ka.z + qa[0].w*ka.w
                 + qb[0].x*kb.x + qb[0].y*kb.y + qb[0].z*kb.z + qb[0].w*kb.w;
        float a1 = qa[1].x*ka.x + qa[1].y*ka.y + qa[1].z*ka.z + qa[1].w*ka.w
                 + qb[1].x*kb.x + qb[1].y*kb.y + qb[1].z*kb.z + qb[1].w*kb.w;
        float a2 = qa[2].x*ka.x + qa[2].y*ka.y + qa[2].z*ka.z + qa[2].w*ka.w
                 + qb[2].x*kb.x + qb[2].y*kb.y + qb[2].z*kb.z + qb[2].w*kb.w;
        float a3 = qa[3].x*ka.x + qa[3].y*ka.y + qa[3].z*ka.z + qa[3].w*ka.w
                 + qb[3].x*kb.x + qb[3].y*kb.y + qb[3].z*kb.z + qb[3].w*kb.w;
        a0 += dppf<DPP_XOR1>(a0); a1 += dppf<DPP_XOR1>(a1);
        a2 += dppf<DPP_XOR1>(a2); a3 += dppf<DPP_XOR1>(a3);
        a0 += dppf<DPP_XOR2>(a0); a1 += dppf<DPP_XOR2>(a1);
        a2 += dppf<DPP_XOR2>(a2); a3 += dppf<DPP_XOR2>(a3);
        float s = (l16 & 2) ? ((l16 & 1) ? a3 : a2) : ((l16 & 1) ? a1 : a0);
        s += dppf<DPP_ROR4>(s);
        s += dppf<DPP_ROR8>(s);
        const float pe = act ? __expf(s) : 0.f;   // q pre-scaled; |s|<~6: fp32-safe
        psum += pe;
        const float p0 = dppf<DPP_BC0>(pe);
        const float p1 = dppf<DPP_BC1>(pe);
        const float p2 = dppf<DPP_BC2>(pe);
        const float p3 = dppf<DPP_BC3>(pe);
        oa[0].x += p0*va.x; oa[0].y += p0*va.y; oa[0].z += p0*va.z; oa[0].w += p0*va.w;
        ob[0].x += p0*vb.x; ob[0].y += p0*vb.y; ob[0].z += p0*vb.z; ob[0].w += p0*vb.w;
        oa[1].x += p1*va.x; oa[1].y += p1*va.y; oa[1].z += p1*va.z; oa[1].w += p1*va.w;
        ob[1].x += p1*vb.x; ob[1].y += p1*vb.y; ob[1].z += p1*vb.z; ob[1].w += p1*vb.w;
        oa[2].x += p2*va.x; oa[2].y += p2*va.y; oa[2].z += p2*va.z; oa[2].w += p2*va.w;
        ob[2].x += p2*vb.x; ob[2].y += p2*vb.y; ob[2].z += p2*vb.z; ob[2].w += p2*vb.w;
        oa[3].x += p3*va.x; oa[3].y += p3*va.y; oa[3].z += p3*va.z; oa[3].w += p3*va.w;
        ob[3].x += p3*vb.x; ob[3].y += p3*vb.y; ob[3].z += p3*vb.z; ob[3].w += p3*vb.w;
    };

    const bool last_chunk = (t0 + CH >= L);

    if (!last_chunk) {
        // depth-3 pipeline: two pages in flight beyond the consumed one
        size_t r0 = ((size_t)s_pages[0] * NP + grp) * 32 + l16;
        size_t r1 = ((size_t)s_pages[1] * NP + grp) * 32 + l16;
        float4 ka0 = kc4[r0], kb0 = kc4[r0 + 16], va0 = vc4[r0], vb0 = vc4[r0 + 16];
        float4 ka1 = kc4[r1], kb1 = kc4[r1 + 16], va1 = vc4[r1], vb1 = vc4[r1 + 16];
        #pragma unroll 2
        for (int p = 0; p < CH / NP - 2; ++p) {
            const size_t rn = ((size_t)s_pages[p + 2] * NP + grp) * 32 + l16;
            const float4 nka = kc4[rn], nkb = kc4[rn + 16];
            const float4 nva = vc4[rn], nvb = vc4[rn + 16];
            proc(ka0, kb0, va0, vb0, true);
            ka0 = ka1; kb0 = kb1; va0 = va1; vb0 = vb1;
            ka1 = nka; kb1 = nkb; va1 = nva; vb1 = nvb;
        }
        proc(ka0, kb0, va0, vb0, true);
        proc(ka1, kb1, va1, vb1, true);
    } else {
        const int nf = (n - 1) & ~(NP - 1);   // full pages strictly before the last token

        // tail-token loads issued FIRST: latency hides under the page loop.
        const int t = nf + grp;
        const bool act = (t < n);
        const bool isnew = (t0 + t == seq);
        const float4* kp = isnew ? knew4 : kc4;
        const float4* vp = isnew ? vnew4 : vc4;
        const size_t trow = isnew ? (size_t)(b * NHKV + h) * 32
                                  : ((size_t)s_pages[t >> 4] * NP + (t & 15)) * 32;
        const float4 tka = kp[trow + l16];
        const float4 tkb = kp[trow + 16 + l16];
        const float4 tva = vp[trow + l16];
        const float4 tvb = vp[trow + 16 + l16];

        // depth-2 rotating pipeline over the variable-count full pages
        const int npg = nf >> 4;
        if (npg > 0) {
            size_t r = ((size_t)s_pages[0] * NP + grp) * 32 + l16;
            float4 ka = kc4[r], kb = kc4[r + 16];
            float4 va = vc4[r], vb = vc4[r + 16];
            for (int p = 0; p + 1 < npg; ++p) {
                const size_t rn = ((size_t)s_pages[p + 1] * NP + grp) * 32 + l16;
                const float4 nka = kc4[rn], nkb = kc4[rn + 16];
                const float4 nva = vc4[rn], nvb = vc4[rn + 16];
                proc(ka, kb, va, vb, true);
                ka = nka; kb = nkb; va = nva; vb = nvb;
            }
            proc(ka, kb, va, vb, true);
        }
        proc(tka, tkb, tva, tvb, act);
    }

    // reduce across the 4 groups of each wave (once per chunk; DS ok here)
    #pragma unroll
    for (int g = 0; g < NG; ++g) {
        oa[g].x += __shfl_xor(oa[g].x, 16); oa[g].y += __shfl_xor(oa[g].y, 16);
        oa[g].z += __shfl_xor(oa[g].z, 16); oa[g].w += __shfl_xor(oa[g].w, 16);
        ob[g].x += __shfl_xor(ob[g].x, 16); ob[g].y += __shfl_xor(ob[g].y, 16);
        ob[g].z += __shfl_xor(ob[g].z, 16); ob[g].w += __shfl_xor(ob[g].w, 16);
        oa[g].x += __shfl_xor(oa[g].x, 32); oa[g].y += __shfl_xor(oa[g].y, 32);
        oa[g].z += __shfl_xor(oa[g].z, 32); oa[g].w += __shfl_xor(oa[g].w, 32);
        ob[g].x += __shfl_xor(ob[g].x, 32); ob[g].y += __shfl_xor(ob[g].y, 32);
        ob[g].z += __shfl_xor(ob[g].z, 32); ob[g].w += __shfl_xor(ob[g].w, 32);
    }
    psum += __shfl_xor(psum, 16);
    psum += __shfl_xor(psum, 32);

    const int wv = tid >> 6;
    if ((tid & 63) < 16) {
        #pragma unroll
        for (int g = 0; g < NG; ++g) {
            *reinterpret_cast<float4*>(&s_part[wv][g][4 * l16]) = oa[g];
            *reinterpret_cast<float4*>(&s_part[wv][g][64 + 4 * l16]) = ob[g];
        }
    }
    if ((tid & 63) < NG) s_sums[wv][tid & 3] = psum;
    __syncthreads();

    if (nc == 1) {
        // single-chunk bh: normalized output directly, no ws round-trip
        for (int idx = tid; idx < NG * ND; idx += 256) {
            const int g = idx >> 7;
            const int d = idx & 127;
            const float num = s_part[0][g][d] + s_part[1][g][d] + s_part[2][g][d] + s_part[3][g][d];
            const float den = s_sums[0][g] + s_sums[1][g] + s_sums[2][g] + s_sums[3][g];
            out[(size_t)(b * NH + h * NG + g) * ND + d] = num / den;
        }
        return;
    }

    for (int idx = tid; idx < NG * ND; idx += 256) {
        const int g = idx >> 7;
        const int d = idx & 127;
        ws_o[((size_t)(bh * MAXC + c) * NG + g) * ND + d] =
            s_part[0][g][d] + s_part[1][g][d] + s_part[2][g][d] + s_part[3][g][d];
    }
    if (tid < NG) {
        ws_l[(size_t)(bh * MAXC + c) * NG + tid] =
            s_sums[0][tid] + s_sums[1][tid] + s_sums[2][tid] + s_sums[3][tid];
    }
}

__global__ __launch_bounds__(512, 2)
void pa_combine(const float* __restrict__ ws_o,
                const float* __restrict__ ws_l,
                const int* __restrict__ bh_seq_lens,
                const int* __restrict__ batch_mapping,
                float* __restrict__ out)
{
    const int bh = blockIdx.x;
    const int b = bh >> 3;
    const int h = bh & 7;
    const int L = bh_seq_lens[batch_mapping[b] * NHKV + h] + 1;
    const int nc = (L + CH - 1) / CH;
    if (nc == 1) return;                 // chunk kernel wrote out directly

    const int tid = threadIdx.x;
    const int g = tid >> 7;
    const int d = tid & 127;

    float num = 0.f, den = 0.f;
    #pragma unroll
    for (int c = 0; c < MAXC; ++c) {
        if (c < nc) {
            num += ws_o[((size_t)(bh * MAXC + c) * NG + g) * ND + d];
            den += ws_l[(size_t)(bh * MAXC + c) * NG + g];
        }
    }
    out[(size_t)(b * NH + h * NG + g) * ND + d] = num / den;
}

extern "C" void kernel_launch(void* const* d_in, const int* in_sizes, int n_in,
                              void* d_out, int out_size, void* d_ws, size_t ws_size,
                              hipStream_t stream) {
    const float* q    = (const float*)d_in[0];
    const float* knew = (const float*)d_in[1];
    const float* vnew = (const float*)d_in[2];
    const float* kc   = (const float*)d_in[3];
    const float* vc   = (const float*)d_in[4];
    const int* seqls  = (const int*)d_in[5];
    const int* ptab   = (const int*)d_in[6];
    const int* bmap   = (const int*)d_in[7];
    float* out        = (float*)d_out;

    float* ws_o = (float*)d_ws;
    float* ws_l = ws_o + (size_t)NB * NHKV * MAXC * NG * ND;

    dim3 grid(NB * NHKV, MAXC);
    pa_chunk<<<grid, 256, 0, stream>>>(q, knew, vnew, kc, vc, seqls, ptab, bmap,
                                       ws_o, ws_l, out);
    pa_combine<<<NB * NHKV, 512, 0, stream>>>(ws_o, ws_l, seqls, bmap, out);
}